// Round 8
// baseline (202.511 us; speedup 1.0000x reference)
//
#include <hip/hip_runtime.h>

#define B_  4
#define C1  256
#define C2  128
#define HH  64
#define WW  64
#define H2  128
#define W2  128

using short8  = __attribute__((ext_vector_type(8))) short;
using floatx4 = __attribute__((ext_vector_type(4))) float;
typedef unsigned short ushort_t;

#define GLOBAL_AS __attribute__((address_space(1)))
#define LDS_AS    __attribute__((address_space(3)))

// ---- workspace layout (bytes) ----
#define W1C_OFF 0u                                   // [kc4][tap4][p2][pwp2][co128][ci64] bf16, granule-swizzled
#define W1C_ELEMS (4 * 4 * 128 * 256)
#define W2C_OFF (W1C_ELEMS * 2u)                     // [tap9][o128][ci128] bf16 (granule-swizzled)
#define W2C_ELEMS (9 * 128 * 128)
#define KG_OFF  (W2C_OFF + W2C_ELEMS * 2u)           // [b][h][tap9][w128] fp32
#define KG_ELEMS (B_ * H2 * 9 * W2)
#define XT_OFF  (KG_OFF + KG_ELEMS * 4u)             // x -> [b][ih][iw][ci] bf16
#define XT_ELEMS (B_ * HH * WW * C1)
#define Y_OFF   (XT_OFF + XT_ELEMS * 2u)             // y -> [b][h][w][c] bf16, granule-swizzled by (w&7)
#define Y_ELEMS (B_ * H2 * W2 * C2)

// prep_kernel section boundaries (blocks of 512 threads) — v8 mappings
#define PREP_W1C_BLKS (W1C_ELEMS / 512)              // 1024
#define PREP_W2C_BLKS (W2C_ELEMS / 512)              // 288
#define PREP_XT_BLKS  (B_ * HH)                      // 256
#define PREP_K_BLKS   (B_ * H2)                      // 512
#define PREP_B0 PREP_W1C_BLKS
#define PREP_B1 (PREP_B0 + PREP_W2C_BLKS)
#define PREP_B2 (PREP_B1 + PREP_XT_BLKS)
#define PREP_B3 (PREP_B2 + PREP_K_BLKS)              // 2080 total

static __device__ __forceinline__ ushort_t f2bf(float f) {
    union { float f; unsigned u; } v; v.f = f;
    unsigned r = v.u + 0x7FFFu + ((v.u >> 16) & 1u);   // RNE
    return (ushort_t)(r >> 16);
}

// ---------------------------------------------------------------------------
// Fused prep: 4 independent sections co-scheduled in ONE launch.
//  sec 0: w1 -> w1s[kc][tap][p][pwp][co][ci64], swizzled. v8 mapping
//         (coalesced 2B writes; scattered reads are L2-absorbed, w1 = 4MB).
//  sec 1: w2 -> w2c[tap][o][ci] (flip baked, swizzled). v8 mapping.
//  sec 2: x (NCHW fp32) -> xT[b][ih][iw][ci] bf16 (LDS transpose)
//  sec 3: kg guide kernel — shfl-based neighbor sharing (VMEM 10 -> ~4 per c,
//         bit-identical values: shuffled value == loaded value).
// ---------------------------------------------------------------------------
__global__ __launch_bounds__(512) void prep_kernel(const float* __restrict__ w1,
                                                   ushort_t* __restrict__ w1c,
                                                   const float* __restrict__ w2,
                                                   ushort_t* __restrict__ w2c,
                                                   const float* __restrict__ x,
                                                   ushort_t* __restrict__ xT,
                                                   const float* __restrict__ guide,
                                                   float* __restrict__ kg) {
    const int bid = blockIdx.x;
    const int tid = threadIdx.x;
    __shared__ __align__(16) char smem[18432];       // max(tile 17408, part 18432)

    if (bid < PREP_B0) {
        // ---- w1 prep (v8: output-contiguous, coalesced writes)
        const int i   = bid * 512 + tid;
        const int sub = i & 7;
        const int gs  = (i >> 3) & 7;
        const int co  = (i >> 6) & 127;
        const int pwp = (i >> 13) & 1;
        const int p   = (i >> 14) & 1;
        const int tap = (i >> 15) & 3;
        const int kc  = (i >> 17) & 3;
        const int ci  = kc * 64 + (((gs ^ (co & 7)) << 3) | sub);
        const int kh  = p + 2 * (tap >> 1);
        const int kw  = pwp + 2 * (tap & 1);
        w1c[i] = f2bf(w1[((ci * C2 + co) * 4 + kh) * 4 + kw]);
    } else if (bid < PREP_B1) {
        // ---- w2 prep (v8 mapping)
        const int i   = (bid - PREP_B0) * 512 + tid;
        const int ci  = i & 127;
        const int o   = (i >> 7) & 127;
        const int tap = i >> 14;
        const int fi  = 2 - tap / 3;
        const int fj  = 2 - tap % 3;
        const int gs  = ((((ci >> 3) ^ (o & 7)) << 3) | (ci & 7));
        w2c[tap * 16384 + o * 128 + gs] = f2bf(w2[((ci * C2 + o) * 3 + fi) * 3 + fj]);
    } else if (bid < PREP_B2) {
        // ---- x transpose: (b, ih) per block, 2 chunks of 128 ci
        const int idx = bid - PREP_B1;
        const int ih  = idx & 63;
        const int b   = idx >> 6;
        ushort_t* tile = (ushort_t*)smem;            // [iw][cc], stride 136
        for (int chunk = 0; chunk < 2; ++chunk) {
            const int ci0 = chunk * 128;
            if (chunk) __syncthreads();
#pragma unroll
            for (int it = 0; it < 16; ++it) {
                const int cc = it * 8 + (tid >> 6);
                const int iw = tid & 63;
                const float v = x[(((size_t)b * C1 + ci0 + cc) * HH + ih) * WW + iw];
                tile[iw * 136 + cc] = f2bf(v);
            }
            __syncthreads();
#pragma unroll
            for (int it = 0; it < 2; ++it) {
                const int i  = it * 512 + tid;
                const int iw = i >> 4;
                const int t  = i & 15;
                const int4 v = *reinterpret_cast<const int4*>(&tile[iw * 136 + t * 8]);
                *reinterpret_cast<int4*>(
                    &xT[(((size_t)(b * HH + ih) * WW) + iw) * C1 + ci0 + t * 8]) = v;
            }
        }
    } else {
        // ---- guide kernel k: shfl-based. Same accumulation order as before;
        // left/right neighbors come from shfl (bit-identical to a load).
        const int idx = bid - PREP_B2;
        const int h   = idx & 127;
        const int b   = idx >> 7;
        const int cq  = tid >> 7;
        const int n   = tid & 127;
        const int l   = tid & 63;                    // lane within wave

        float acc[9];
#pragma unroll
        for (int t = 0; t < 9; ++t) acc[t] = 0.f;

        const float* gb = guide + (size_t)b * C2 * H2 * W2;
        for (int c = cq * 32; c < cq * 32 + 32; ++c) {
            const float gc = gb[((size_t)c * H2 + h) * W2 + n];
#pragma unroll
            for (int di = 0; di < 3; ++di) {
                const int hh = h + di - 1;
                float cen = 0.f, lef = 0.f, rig = 0.f;
                if (hh >= 0 && hh < H2) {            // block-uniform branch
                    const float* gr = gb + ((size_t)c * H2 + hh) * W2;
                    cen = gr[n];
                    lef = __shfl_up(cen, 1);
                    rig = __shfl_down(cen, 1);
                    if (l == 0)  lef = (n == 0)   ? 0.f : gr[n - 1];
                    if (l == 63) rig = (n == 127) ? 0.f : gr[n + 1];
                }
                const float d0 = lef - gc;
                const float d1 = cen - gc;
                const float d2 = rig - gc;
                acc[di * 3 + 0] += d0 * d0;
                acc[di * 3 + 1] += d1 * d1;
                acc[di * 3 + 2] += d2 * d2;
            }
        }

        float (*part)[9][128] = (float (*)[9][128])smem;
#pragma unroll
        for (int t = 0; t < 9; ++t) part[cq][t][n] = acc[t];
        __syncthreads();

        for (int i = tid; i < 1152; i += 512) {
            const int t  = i >> 7;
            const int nn = i & 127;
            const float s = part[0][t][nn] + part[1][t][nn] + part[2][t][nn] + part[3][t][nn];
            kg[(size_t)(b * H2 + h) * 1152 + i] = __expf(-0.5f * s);
        }
    }
}

// ---------------------------------------------------------------------------
// Deconv MFMA v6 + XCD swizzle (no setprio): one 512-thread block per (b, pr).
// Output 128co x 256pix. Grid 64x4 = 256 = 1 block/CU.
// ---------------------------------------------------------------------------
__global__ __launch_bounds__(512, 2) void deconv_mfma(const ushort_t* __restrict__ xT,
                                                      const ushort_t* __restrict__ w1s,
                                                      const float* __restrict__ b1,
                                                      ushort_t* __restrict__ y) {
    const int bx = blockIdx.x;
    const int pr = ((bx & 7) << 3) | (bx >> 3);      // XCD-contiguous pr ranges
    const int b  = blockIdx.y;
    const int base_oh = (pr >> 1) * 4 + (pr & 1);
    const int p    = (base_oh + 1) & 1;
    const int ihA0 = (base_oh + 1 - p) >> 1;

    const int tid  = threadIdx.x;
    const int lane = tid & 63;
    const int wave = tid >> 6;          // 0..7
    const int pwc  = wave >> 2;         // output-column parity half
    const int q    = wave & 3;          // quadrant
    const int wm   = (q & 1) * 64;
    const int wn   = (q >> 1) * 64;
    const int quad = lane >> 4;
    const int l15  = lane & 15;
    const int pwp  = 1 - pwc;

    __shared__ __align__(16) ushort_t BS[3 * 64 * 256];      // 98304 B
    __shared__ __align__(16) ushort_t AS[2][2 * 128 * 64];   // 2 x 32768 B

    // ---- prologue: issue A(phase 0) via global_load_lds (zero registers)
    {
        const ushort_t* src = w1s + (size_t)(0 * 2 + p) * 16384;
#pragma unroll
        for (int it = 0; it < 4; ++it) {
            const int i = it * 512 + tid;
            __builtin_amdgcn_global_load_lds((const GLOBAL_AS void*)(src + i * 8),
                                             (LDS_AS void*)(&AS[0][i * 8]), 16, 0, 0);
        }
    }
    // ---- stage B slab: rows ihA0-1..ihA0+1, 6144 granules, zero OOB rows
#pragma unroll
    for (int it = 0; it < 12; ++it) {
        const int i   = it * 512 + tid;      // 0..6143
        const int pix = i >> 5;              // 0..191
        const int g   = i & 31;
        const int sr  = pix >> 6;
        const int iw  = pix & 63;
        const int ih  = ihA0 - 1 + sr;
        int4 v = make_int4(0, 0, 0, 0);
        if (ih >= 0 && ih < HH)
            v = *reinterpret_cast<const int4*>(
                &xT[(((size_t)(b * HH + ih) * WW) + iw) * C1 + g * 8]);
        *reinterpret_cast<int4*>(&BS[pix * 256 + ((g ^ (pix & 7)) << 3)]) = v;
    }
    __syncthreads();

    floatx4 acc[4][4];
#pragma unroll
    for (int mi = 0; mi < 4; ++mi)
#pragma unroll
        for (int ni = 0; ni < 4; ++ni) acc[mi][ni] = (floatx4)0.f;

#pragma unroll 1
    for (int ph = 0; ph < 16; ++ph) {        // ph = kc*4 + tap (v2 order)
        const int kc  = ph >> 2;
        const int tap = ph & 3;
        const int cur = ph & 1;
        // ---- issue next A into the other buffer (flies under this GEMM)
        if (ph < 15) {
            const ushort_t* src = w1s + (size_t)((ph + 1) * 2 + p) * 16384;
#pragma unroll
            for (int it = 0; it < 4; ++it) {
                const int i = it * 512 + tid;
                __builtin_amdgcn_global_load_lds((const GLOBAL_AS void*)(src + i * 8),
                                                 (LDS_AS void*)(&AS[cur ^ 1][i * 8]), 16, 0, 0);
            }
        }
        const int th = tap >> 1, tw = tap & 1;
#pragma unroll
        for (int k2 = 0; k2 < 2; ++k2) {
            short8 af[4], bfr[4];
#pragma unroll
            for (int mi = 0; mi < 4; ++mi) {
                const int row = wm + mi * 16 + l15;
                af[mi] = *reinterpret_cast<const short8*>(
                    &AS[cur][pwp * 8192 + row * 64 + (((k2 * 4 + quad) ^ (row & 7)) << 3)]);
            }
#pragma unroll
            for (int ni = 0; ni < 4; ++ni) {
                const int n   = wn + ni * 16 + l15;
                const int rh  = n >> 6;
                const int n64 = n & 63;
                const int iw  = n64 + pwc - tw;
                const int pix = (rh - th + 1) * 64 + (iw & 63);
                const short8 t = *reinterpret_cast<const short8*>(
                    &BS[pix * 256 + kc * 64 + (((k2 * 4 + quad) ^ (pix & 7)) << 3)]);
                const bool ok = (iw >= 0) && (iw < WW);
                bfr[ni] = ok ? t : (short8)0;
            }
#pragma unroll
            for (int mi = 0; mi < 4; ++mi)
#pragma unroll
                for (int ni = 0; ni < 4; ++ni)
                    acc[mi][ni] = __builtin_amdgcn_mfma_f32_16x16x32_bf16(
                        af[mi], bfr[ni], acc[mi][ni], 0, 0, 0);
        }
        __syncthreads();   // AS[cur] readers done; AS[cur^1] resident (vmcnt drain)
    }

    // ---- epilogue: transpose in LDS (reuse BS) -> y[b][oh][ow][swz(co)] bf16
    ushort_t* Ot = BS;                       // [256 pix][128 co], stride 136
#pragma unroll
    for (int mi = 0; mi < 4; ++mi)
#pragma unroll
        for (int ni = 0; ni < 4; ++ni) {
            const int n = wn + ni * 16 + l15;
#pragma unroll
            for (int r = 0; r < 4; ++r) {
                const int co = wm + mi * 16 + quad * 4 + r;
                Ot[(pwc * 128 + n) * 136 + co] = f2bf(acc[mi][ni][r] + b1[co]);
            }
        }
    __syncthreads();
#pragma unroll
    for (int it = 0; it < 8; ++it) {
        const int i    = it * 512 + tid;
        const int n_   = i >> 4;             // 0..255
        const int t    = i & 15;
        const int half = n_ >> 7;
        const int n    = n_ & 127;
        const int rh   = n >> 6;
        const int n64  = n & 63;
        const int oh   = base_oh + 2 * rh;
        const int ow   = 2 * n64 + half;
        const int4 v = *reinterpret_cast<const int4*>(&Ot[n_ * 136 + t * 8]);
        *reinterpret_cast<int4*>(
            &y[(((size_t)(b * H2 + oh) * W2) + ow) * C2 + ((t ^ (ow & 7)) << 3)]) = v;
    }
}

// ---------------------------------------------------------------------------
// PAC MFMA v7 + XCD swizzle (no setprio): one 512-thread block per (b, 2 rows).
// Grid 64x4 = 256 = 1 block/CU. LDS = 3 y-slabs + AS[2] = 160 KiB.
// ---------------------------------------------------------------------------
__global__ __launch_bounds__(512, 2) void pac_mfma(const ushort_t* __restrict__ y,
                                                   const float* __restrict__ kg,
                                                   const ushort_t* __restrict__ w2c,
                                                   const float* __restrict__ b2,
                                                   float* __restrict__ out) {
    const int bx   = blockIdx.x;
    const int hblk = ((bx & 7) << 3) | (bx >> 3);    // XCD-contiguous h ranges
    const int b    = blockIdx.y;
    const int h0   = hblk * 2;

    const int tid  = threadIdx.x;
    const int lane = tid & 63;
    const int wave = tid >> 6;          // 0..7
    const int rsub = wave >> 2;         // which of the 2 output rows
    const int q    = wave & 3;          // quadrant
    const int wm   = (q & 1) * 64;
    const int wn   = (q >> 1) * 64;
    const int quad = lane >> 4;
    const int l15  = lane & 15;
    const int h    = h0 + rsub;

    __shared__ __align__(16) ushort_t SLAB[3][128 * 128];  // rotating y rows
    __shared__ __align__(16) ushort_t AS[2][128 * 128];    // w2c double buffer

    // ---- prologue: issue AS[0] (tap0) + slabs s=0,1,2 (all linear DMA)
#pragma unroll
    for (int it = 0; it < 4; ++it) {
        const int i = it * 512 + tid;
        __builtin_amdgcn_global_load_lds((const GLOBAL_AS void*)(w2c + i * 8),
                                         (LDS_AS void*)(&AS[0][i * 8]), 16, 0, 0);
    }
#pragma unroll 1
    for (int s = 0; s < 3; ++s) {
        const int hh = h0 - 1 + s;
        if (hh < 0) continue;                          // block-uniform (s=0 @ h0==0)
        const ushort_t* ysrc = y + (size_t)(b * H2 + hh) * W2 * C2;
#pragma unroll
        for (int it = 0; it < 4; ++it) {
            const int i = it * 512 + tid;
            __builtin_amdgcn_global_load_lds((const GLOBAL_AS void*)(ysrc + i * 8),
                                             (LDS_AS void*)(&SLAB[s][i * 8]), 16, 0, 0);
        }
    }
    __syncthreads();

    float out_acc[4][4][4];
#pragma unroll
    for (int mi = 0; mi < 4; ++mi)
#pragma unroll
        for (int ni = 0; ni < 4; ++ni)
#pragma unroll
            for (int r = 0; r < 4; ++r) out_acc[mi][ni][r] = 0.f;

#pragma unroll 1
    for (int di = 0; di < 3; ++di) {
        // ---- stream slab s3 (row h0+2) into buffer 0 during di=1:
        // buffer 0's readers (di=0) finished at the di=0 end barrier.
        if (di == 1 && h0 + 2 < H2) {
            const ushort_t* ysrc = y + (size_t)(b * H2 + h0 + 2) * W2 * C2;
#pragma unroll
            for (int it = 0; it < 4; ++it) {
                const int i = it * 512 + tid;
                __builtin_amdgcn_global_load_lds((const GLOBAL_AS void*)(ysrc + i * 8),
                                                 (LDS_AS void*)(&SLAB[0][i * 8]), 16, 0, 0);
            }
        }
        const int hh  = h + di - 1;                     // per-wave row validity
        const bool hok = (hh >= 0) && (hh < H2);
        const ushort_t* SB = &SLAB[(rsub + di) % 3][0];
#pragma unroll 1
        for (int dj = 0; dj < 3; ++dj) {
            const int tap = di * 3 + dj;
            // ---- issue AS[tap+1] into the other buffer (flies under GEMM)
            if (tap < 8) {
                const ushort_t* wsrc = w2c + (size_t)(tap + 1) * 16384;
#pragma unroll
                for (int it = 0; it < 4; ++it) {
                    const int i = it * 512 + tid;
                    __builtin_amdgcn_global_load_lds((const GLOBAL_AS void*)(wsrc + i * 8),
                                                     (LDS_AS void*)(&AS[(tap + 1) & 1][i * 8]),
                                                     16, 0, 0);
                }
            }

            float kv[4];
#pragma unroll
            for (int ni = 0; ni < 4; ++ni)
                kv[ni] = kg[(size_t)(b * H2 + h) * 1152 + tap * 128 + wn + ni * 16 + l15];

            floatx4 acc[4][4];
#pragma unroll
            for (int mi = 0; mi < 4; ++mi)
#pragma unroll
                for (int ni = 0; ni < 4; ++ni) acc[mi][ni] = (floatx4)0.f;

            const ushort_t* AScur = &AS[tap & 1][0];
#pragma unroll
            for (int kc = 0; kc < 4; ++kc) {
                short8 af[4], bfr[4];
#pragma unroll
                for (int mi = 0; mi < 4; ++mi) {
                    const int row = wm + mi * 16 + l15;
                    af[mi] = *reinterpret_cast<const short8*>(
                        &AScur[row * 128 + (((kc * 4 + quad) ^ (row & 7)) << 3)]);
                }
#pragma unroll
                for (int ni = 0; ni < 4; ++ni) {
                    const int col  = wn + ni * 16 + l15 + dj - 1;
                    const int colc = col & 127;
                    const short8 t = *reinterpret_cast<const short8*>(
                        &SB[colc * 128 + (((kc * 4 + quad) ^ (colc & 7)) << 3)]);
                    const bool ok = hok && (col >= 0) && (col < W2);
                    bfr[ni] = ok ? t : (short8)0;
                }
#pragma unroll
                for (int mi = 0; mi < 4; ++mi)
#pragma unroll
                    for (int ni = 0; ni < 4; ++ni)
                        acc[mi][ni] = __builtin_amdgcn_mfma_f32_16x16x32_bf16(
                            af[mi], bfr[ni], acc[mi][ni], 0, 0, 0);
            }
            // ---- scale by k_tap[w] and accumulate (adds exact 0 for edge taps)
#pragma unroll
            for (int mi = 0; mi < 4; ++mi)
#pragma unroll
                for (int ni = 0; ni < 4; ++ni)
#pragma unroll
                    for (int r = 0; r < 4; ++r)
                        out_acc[mi][ni][r] += kv[ni] * acc[mi][ni][r];

            __syncthreads();   // AS[tap&1] readers done; AS[(tap+1)&1] resident
        }
    }

    // ---- final store: out NCHW fp32
#pragma unroll
    for (int mi = 0; mi < 4; ++mi)
#pragma unroll
        for (int ni = 0; ni < 4; ++ni) {
            const int w = wn + ni * 16 + l15;
#pragma unroll
            for (int r = 0; r < 4; ++r) {
                const int o = wm + mi * 16 + quad * 4 + r;
                out[(((size_t)b * C2 + o) * H2 + h) * W2 + w] = out_acc[mi][ni][r] + b2[o];
            }
        }
}

extern "C" void kernel_launch(void* const* d_in, const int* in_sizes, int n_in,
                              void* d_out, int out_size, void* d_ws, size_t ws_size,
                              hipStream_t stream) {
    const float* x     = (const float*)d_in[0];
    const float* guide = (const float*)d_in[1];
    const float* w1    = (const float*)d_in[2];
    const float* b1    = (const float*)d_in[3];
    const float* w2    = (const float*)d_in[4];
    const float* b2    = (const float*)d_in[5];
    float* out = (float*)d_out;

    ushort_t* w1c = (ushort_t*)((char*)d_ws + W1C_OFF);
    ushort_t* w2c = (ushort_t*)((char*)d_ws + W2C_OFF);
    float*    kg  = (float*)((char*)d_ws + KG_OFF);
    ushort_t* xT  = (ushort_t*)((char*)d_ws + XT_OFF);
    ushort_t* y   = (ushort_t*)((char*)d_ws + Y_OFF);

    prep_kernel<<<PREP_B3, 512, 0, stream>>>(w1, w1c, w2, w2c, x, xT, guide, kg);
    deconv_mfma<<<dim3(64, B_), 512, 0, stream>>>(xT, w1c, b1, y);
    pac_mfma<<<dim3(64, B_), 512, 0, stream>>>(y, kg, w2c, b2, out);
}

// Round 9
// 171.230 us; speedup vs baseline: 1.1827x; 1.1827x over previous
//
#include <hip/hip_runtime.h>

#define B_  4
#define C1  256
#define C2  128
#define HH  64
#define WW  64
#define H2  128
#define W2  128

using short8  = __attribute__((ext_vector_type(8))) short;
using floatx4 = __attribute__((ext_vector_type(4))) float;
typedef unsigned short ushort_t;

#define GLOBAL_AS __attribute__((address_space(1)))
#define LDS_AS    __attribute__((address_space(3)))

// ---- workspace layout (bytes) ----
#define W1C_OFF 0u                                   // [kc4][tap4][p2][pwp2][co128][ci64] bf16, granule-swizzled
#define W1C_ELEMS (4 * 4 * 128 * 256)
#define W2C_OFF (W1C_ELEMS * 2u)                     // [tap9][o128][ci128] bf16 (granule-swizzled)
#define W2C_ELEMS (9 * 128 * 128)
#define KG_OFF  (W2C_OFF + W2C_ELEMS * 2u)           // [b][h][tap9][w128] fp32
#define KG_ELEMS (B_ * H2 * 9 * W2)
#define XT_OFF  (KG_OFF + KG_ELEMS * 4u)             // x -> [b][ih][iw][ci] bf16
#define XT_ELEMS (B_ * HH * WW * C1)
#define Y_OFF   (XT_OFF + XT_ELEMS * 2u)             // y -> [b][h][w][c] bf16, granule-swizzled by (w&7)
#define Y_ELEMS (B_ * H2 * W2 * C2)

// prep_kernel section boundaries (blocks of 512 threads) — v8 mappings
#define PREP_W1C_BLKS (W1C_ELEMS / 512)              // 1024
#define PREP_W2C_BLKS (W2C_ELEMS / 512)              // 288
#define PREP_XT_BLKS  (B_ * HH)                      // 256
#define PREP_K_BLKS   (B_ * H2)                      // 512
#define PREP_B0 PREP_W1C_BLKS
#define PREP_B1 (PREP_B0 + PREP_W2C_BLKS)
#define PREP_B2 (PREP_B1 + PREP_XT_BLKS)
#define PREP_B3 (PREP_B2 + PREP_K_BLKS)              // 2080 total

static __device__ __forceinline__ ushort_t f2bf(float f) {
    union { float f; unsigned u; } v; v.f = f;
    unsigned r = v.u + 0x7FFFu + ((v.u >> 16) & 1u);   // RNE
    return (ushort_t)(r >> 16);
}

// ---------------------------------------------------------------------------
// Fused prep: 4 independent sections co-scheduled in ONE launch.
//  sec 0: w1 -> w1s (v8 mapping: coalesced writes, L2-absorbed reads)
//  sec 1: w2 -> w2c (v8 mapping)
//  sec 2: x -> xT (LDS transpose, v8 mapping)
//  sec 3: kg guide kernel — float4-vectorized (G13): each thread owns 4 cols,
//         1 float4 row load + 2 clamped edge scalars per (c,di). All loads
//         independent & predicated (NO shfl in hot loop — v10 lesson).
// ---------------------------------------------------------------------------
__global__ __launch_bounds__(512) void prep_kernel(const float* __restrict__ w1,
                                                   ushort_t* __restrict__ w1c,
                                                   const float* __restrict__ w2,
                                                   ushort_t* __restrict__ w2c,
                                                   const float* __restrict__ x,
                                                   ushort_t* __restrict__ xT,
                                                   const float* __restrict__ guide,
                                                   float* __restrict__ kg) {
    const int bid = blockIdx.x;
    const int tid = threadIdx.x;
    __shared__ __align__(16) char smem[36864];       // max(tile 17408, part8 36864)

    if (bid < PREP_B0) {
        // ---- w1 prep (v8: output-contiguous, coalesced writes)
        const int i   = bid * 512 + tid;
        const int sub = i & 7;
        const int gs  = (i >> 3) & 7;
        const int co  = (i >> 6) & 127;
        const int pwp = (i >> 13) & 1;
        const int p   = (i >> 14) & 1;
        const int tap = (i >> 15) & 3;
        const int kc  = (i >> 17) & 3;
        const int ci  = kc * 64 + (((gs ^ (co & 7)) << 3) | sub);
        const int kh  = p + 2 * (tap >> 1);
        const int kw  = pwp + 2 * (tap & 1);
        w1c[i] = f2bf(w1[((ci * C2 + co) * 4 + kh) * 4 + kw]);
    } else if (bid < PREP_B1) {
        // ---- w2 prep (v8 mapping)
        const int i   = (bid - PREP_B0) * 512 + tid;
        const int ci  = i & 127;
        const int o   = (i >> 7) & 127;
        const int tap = i >> 14;
        const int fi  = 2 - tap / 3;
        const int fj  = 2 - tap % 3;
        const int gs  = ((((ci >> 3) ^ (o & 7)) << 3) | (ci & 7));
        w2c[tap * 16384 + o * 128 + gs] = f2bf(w2[((ci * C2 + o) * 3 + fi) * 3 + fj]);
    } else if (bid < PREP_B2) {
        // ---- x transpose: (b, ih) per block, 2 chunks of 128 ci
        const int idx = bid - PREP_B1;
        const int ih  = idx & 63;
        const int b   = idx >> 6;
        ushort_t* tile = (ushort_t*)smem;            // [iw][cc], stride 136
        for (int chunk = 0; chunk < 2; ++chunk) {
            const int ci0 = chunk * 128;
            if (chunk) __syncthreads();
#pragma unroll
            for (int it = 0; it < 16; ++it) {
                const int cc = it * 8 + (tid >> 6);
                const int iw = tid & 63;
                const float v = x[(((size_t)b * C1 + ci0 + cc) * HH + ih) * WW + iw];
                tile[iw * 136 + cc] = f2bf(v);
            }
            __syncthreads();
#pragma unroll
            for (int it = 0; it < 2; ++it) {
                const int i  = it * 512 + tid;
                const int iw = i >> 4;
                const int t  = i & 15;
                const int4 v = *reinterpret_cast<const int4*>(&tile[iw * 136 + t * 8]);
                *reinterpret_cast<int4*>(
                    &xT[(((size_t)(b * HH + ih) * WW) + iw) * C1 + ci0 + t * 8]) = v;
            }
        }
    } else {
        // ---- guide kernel k, float4 path.
        // thread: cq = tid>>7 (c-quarter), csub = (tid&127)>>5, j = tid&31.
        // Owns cols n0..n0+3; iterates 8 channels c = cq*32 + csub*8 + k.
        const int idx = bid - PREP_B2;
        const int h   = idx & 127;
        const int b   = idx >> 7;
        const int r   = tid & 127;
        const int cq  = tid >> 7;
        const int csub = r >> 5;
        const int j   = r & 31;
        const int n0  = j * 4;

        float acc[9][4];
#pragma unroll
        for (int t = 0; t < 9; ++t)
#pragma unroll
            for (int s = 0; s < 4; ++s) acc[t][s] = 0.f;

        const float* gb = guide + (size_t)b * C2 * H2 * W2;
        const int li = (n0 > 0) ? n0 - 1 : 0;        // clamped edge addresses
        const int ri = (j < 31) ? n0 + 4 : 127;

        for (int k = 0; k < 8; ++k) {
            const int c = cq * 32 + csub * 8 + k;
            const float* gch = gb + ((size_t)c * H2 + h) * W2;
            const float4 gc4 = *reinterpret_cast<const float4*>(&gch[n0]);
#pragma unroll
            for (int di = 0; di < 3; ++di) {
                const int hh = h + di - 1;
                const bool rv = (hh >= 0) && (hh < H2);
                const float* gr = gb + ((size_t)c * H2 + (rv ? hh : 0)) * W2;
                const float4 row = *reinterpret_cast<const float4*>(&gr[n0]);
                const float le = gr[li];
                const float ri_ = gr[ri];
                // validity: row rv; left col valid iff n0>0; right iff j<31
                const float r0 = rv ? row.x : 0.f;
                const float r1 = rv ? row.y : 0.f;
                const float r2 = rv ? row.z : 0.f;
                const float r3 = rv ? row.w : 0.f;
                const float zl = (rv && n0 > 0)  ? le  : 0.f;
                const float zr = (rv && j < 31)  ? ri_ : 0.f;
                const float lef[4] = { zl, r0, r1, r2 };
                const float cen[4] = { r0, r1, r2, r3 };
                const float rig[4] = { r1, r2, r3, zr };
                const float gcs[4] = { gc4.x, gc4.y, gc4.z, gc4.w };
#pragma unroll
                for (int s = 0; s < 4; ++s) {
                    const float d0 = lef[s] - gcs[s];
                    const float d1 = cen[s] - gcs[s];
                    const float d2 = rig[s] - gcs[s];
                    acc[di * 3 + 0][s] += d0 * d0;
                    acc[di * 3 + 1][s] += d1 * d1;
                    acc[di * 3 + 2][s] += d2 * d2;
                }
            }
        }

        // csub-pair reduce within wave (lanes l and l^32 hold same j)
#pragma unroll
        for (int t = 0; t < 9; ++t)
#pragma unroll
            for (int s = 0; s < 4; ++s)
                acc[t][s] += __shfl_xor(acc[t][s], 32);

        // part[8 waves][9 taps][128 cols]
        float (*part)[9][128] = (float (*)[9][128])smem;
        const int w = tid >> 6;
        const int l = tid & 63;
        if (l < 32) {
#pragma unroll
            for (int t = 0; t < 9; ++t)
                *reinterpret_cast<float4*>(&part[w][t][l * 4]) =
                    make_float4(acc[t][0], acc[t][1], acc[t][2], acc[t][3]);
        }
        __syncthreads();

        for (int i = tid; i < 1152; i += 512) {
            const int t  = i >> 7;
            const int nn = i & 127;
            float s = 0.f;
#pragma unroll
            for (int ww = 0; ww < 8; ++ww) s += part[ww][t][nn];
            kg[(size_t)(b * H2 + h) * 1152 + i] = __expf(-0.5f * s);
        }
    }
}

// ---------------------------------------------------------------------------
// Deconv MFMA v6 + XCD swizzle (v8, known-good): one 512-thread block per
// (b, pr). Output 128co x 256pix. Grid 64x4 = 256 = 1 block/CU.
// ---------------------------------------------------------------------------
__global__ __launch_bounds__(512, 2) void deconv_mfma(const ushort_t* __restrict__ xT,
                                                      const ushort_t* __restrict__ w1s,
                                                      const float* __restrict__ b1,
                                                      ushort_t* __restrict__ y) {
    const int bx = blockIdx.x;
    const int pr = ((bx & 7) << 3) | (bx >> 3);      // XCD-contiguous pr ranges
    const int b  = blockIdx.y;
    const int base_oh = (pr >> 1) * 4 + (pr & 1);
    const int p    = (base_oh + 1) & 1;
    const int ihA0 = (base_oh + 1 - p) >> 1;

    const int tid  = threadIdx.x;
    const int lane = tid & 63;
    const int wave = tid >> 6;          // 0..7
    const int pwc  = wave >> 2;         // output-column parity half
    const int q    = wave & 3;          // quadrant
    const int wm   = (q & 1) * 64;
    const int wn   = (q >> 1) * 64;
    const int quad = lane >> 4;
    const int l15  = lane & 15;
    const int pwp  = 1 - pwc;

    __shared__ __align__(16) ushort_t BS[3 * 64 * 256];      // 98304 B
    __shared__ __align__(16) ushort_t AS[2][2 * 128 * 64];   // 2 x 32768 B

    // ---- prologue: issue A(phase 0) via global_load_lds (zero registers)
    {
        const ushort_t* src = w1s + (size_t)(0 * 2 + p) * 16384;
#pragma unroll
        for (int it = 0; it < 4; ++it) {
            const int i = it * 512 + tid;
            __builtin_amdgcn_global_load_lds((const GLOBAL_AS void*)(src + i * 8),
                                             (LDS_AS void*)(&AS[0][i * 8]), 16, 0, 0);
        }
    }
    // ---- stage B slab: rows ihA0-1..ihA0+1, 6144 granules, zero OOB rows
#pragma unroll
    for (int it = 0; it < 12; ++it) {
        const int i   = it * 512 + tid;      // 0..6143
        const int pix = i >> 5;              // 0..191
        const int g   = i & 31;
        const int sr  = pix >> 6;
        const int iw  = pix & 63;
        const int ih  = ihA0 - 1 + sr;
        int4 v = make_int4(0, 0, 0, 0);
        if (ih >= 0 && ih < HH)
            v = *reinterpret_cast<const int4*>(
                &xT[(((size_t)(b * HH + ih) * WW) + iw) * C1 + g * 8]);
        *reinterpret_cast<int4*>(&BS[pix * 256 + ((g ^ (pix & 7)) << 3)]) = v;
    }
    __syncthreads();

    floatx4 acc[4][4];
#pragma unroll
    for (int mi = 0; mi < 4; ++mi)
#pragma unroll
        for (int ni = 0; ni < 4; ++ni) acc[mi][ni] = (floatx4)0.f;

#pragma unroll 1
    for (int ph = 0; ph < 16; ++ph) {        // ph = kc*4 + tap (v2 order)
        const int kc  = ph >> 2;
        const int tap = ph & 3;
        const int cur = ph & 1;
        // ---- issue next A into the other buffer (flies under this GEMM)
        if (ph < 15) {
            const ushort_t* src = w1s + (size_t)((ph + 1) * 2 + p) * 16384;
#pragma unroll
            for (int it = 0; it < 4; ++it) {
                const int i = it * 512 + tid;
                __builtin_amdgcn_global_load_lds((const GLOBAL_AS void*)(src + i * 8),
                                                 (LDS_AS void*)(&AS[cur ^ 1][i * 8]), 16, 0, 0);
            }
        }
        const int th = tap >> 1, tw = tap & 1;
#pragma unroll
        for (int k2 = 0; k2 < 2; ++k2) {
            short8 af[4], bfr[4];
#pragma unroll
            for (int mi = 0; mi < 4; ++mi) {
                const int row = wm + mi * 16 + l15;
                af[mi] = *reinterpret_cast<const short8*>(
                    &AS[cur][pwp * 8192 + row * 64 + (((k2 * 4 + quad) ^ (row & 7)) << 3)]);
            }
#pragma unroll
            for (int ni = 0; ni < 4; ++ni) {
                const int n   = wn + ni * 16 + l15;
                const int rh  = n >> 6;
                const int n64 = n & 63;
                const int iw  = n64 + pwc - tw;
                const int pix = (rh - th + 1) * 64 + (iw & 63);
                const short8 t = *reinterpret_cast<const short8*>(
                    &BS[pix * 256 + kc * 64 + (((k2 * 4 + quad) ^ (pix & 7)) << 3)]);
                const bool ok = (iw >= 0) && (iw < WW);
                bfr[ni] = ok ? t : (short8)0;
            }
#pragma unroll
            for (int mi = 0; mi < 4; ++mi)
#pragma unroll
                for (int ni = 0; ni < 4; ++ni)
                    acc[mi][ni] = __builtin_amdgcn_mfma_f32_16x16x32_bf16(
                        af[mi], bfr[ni], acc[mi][ni], 0, 0, 0);
        }
        __syncthreads();   // AS[cur] readers done; AS[cur^1] resident (vmcnt drain)
    }

    // ---- epilogue: transpose in LDS (reuse BS) -> y[b][oh][ow][swz(co)] bf16
    ushort_t* Ot = BS;                       // [256 pix][128 co], stride 136
#pragma unroll
    for (int mi = 0; mi < 4; ++mi)
#pragma unroll
        for (int ni = 0; ni < 4; ++ni) {
            const int n = wn + ni * 16 + l15;
#pragma unroll
            for (int r = 0; r < 4; ++r) {
                const int co = wm + mi * 16 + quad * 4 + r;
                Ot[(pwc * 128 + n) * 136 + co] = f2bf(acc[mi][ni][r] + b1[co]);
            }
        }
    __syncthreads();
#pragma unroll
    for (int it = 0; it < 8; ++it) {
        const int i    = it * 512 + tid;
        const int n_   = i >> 4;             // 0..255
        const int t    = i & 15;
        const int half = n_ >> 7;
        const int n    = n_ & 127;
        const int rh   = n >> 6;
        const int n64  = n & 63;
        const int oh   = base_oh + 2 * rh;
        const int ow   = 2 * n64 + half;
        const int4 v = *reinterpret_cast<const int4*>(&Ot[n_ * 136 + t * 8]);
        *reinterpret_cast<int4*>(
            &y[(((size_t)(b * H2 + oh) * W2) + ow) * C2 + ((t ^ (ow & 7)) << 3)]) = v;
    }
}

// ---------------------------------------------------------------------------
// PAC MFMA v7 + XCD swizzle (v8, known-good): one 512-thread block per
// (b, 2 rows). Grid 64x4 = 256 = 1 block/CU. LDS = 3 y-slabs + AS[2].
// ---------------------------------------------------------------------------
__global__ __launch_bounds__(512, 2) void pac_mfma(const ushort_t* __restrict__ y,
                                                   const float* __restrict__ kg,
                                                   const ushort_t* __restrict__ w2c,
                                                   const float* __restrict__ b2,
                                                   float* __restrict__ out) {
    const int bx   = blockIdx.x;
    const int hblk = ((bx & 7) << 3) | (bx >> 3);    // XCD-contiguous h ranges
    const int b    = blockIdx.y;
    const int h0   = hblk * 2;

    const int tid  = threadIdx.x;
    const int lane = tid & 63;
    const int wave = tid >> 6;          // 0..7
    const int rsub = wave >> 2;         // which of the 2 output rows
    const int q    = wave & 3;          // quadrant
    const int wm   = (q & 1) * 64;
    const int wn   = (q >> 1) * 64;
    const int quad = lane >> 4;
    const int l15  = lane & 15;
    const int h    = h0 + rsub;

    __shared__ __align__(16) ushort_t SLAB[3][128 * 128];  // rotating y rows
    __shared__ __align__(16) ushort_t AS[2][128 * 128];    // w2c double buffer

    // ---- prologue: issue AS[0] (tap0) + slabs s=0,1,2 (all linear DMA)
#pragma unroll
    for (int it = 0; it < 4; ++it) {
        const int i = it * 512 + tid;
        __builtin_amdgcn_global_load_lds((const GLOBAL_AS void*)(w2c + i * 8),
                                         (LDS_AS void*)(&AS[0][i * 8]), 16, 0, 0);
    }
#pragma unroll 1
    for (int s = 0; s < 3; ++s) {
        const int hh = h0 - 1 + s;
        if (hh < 0) continue;                          // block-uniform (s=0 @ h0==0)
        const ushort_t* ysrc = y + (size_t)(b * H2 + hh) * W2 * C2;
#pragma unroll
        for (int it = 0; it < 4; ++it) {
            const int i = it * 512 + tid;
            __builtin_amdgcn_global_load_lds((const GLOBAL_AS void*)(ysrc + i * 8),
                                             (LDS_AS void*)(&SLAB[s][i * 8]), 16, 0, 0);
        }
    }
    __syncthreads();

    float out_acc[4][4][4];
#pragma unroll
    for (int mi = 0; mi < 4; ++mi)
#pragma unroll
        for (int ni = 0; ni < 4; ++ni)
#pragma unroll
            for (int r = 0; r < 4; ++r) out_acc[mi][ni][r] = 0.f;

#pragma unroll 1
    for (int di = 0; di < 3; ++di) {
        // ---- stream slab s3 (row h0+2) into buffer 0 during di=1:
        // buffer 0's readers (di=0) finished at the di=0 end barrier.
        if (di == 1 && h0 + 2 < H2) {
            const ushort_t* ysrc = y + (size_t)(b * H2 + h0 + 2) * W2 * C2;
#pragma unroll
            for (int it = 0; it < 4; ++it) {
                const int i = it * 512 + tid;
                __builtin_amdgcn_global_load_lds((const GLOBAL_AS void*)(ysrc + i * 8),
                                                 (LDS_AS void*)(&SLAB[0][i * 8]), 16, 0, 0);
            }
        }
        const int hh  = h + di - 1;                     // per-wave row validity
        const bool hok = (hh >= 0) && (hh < H2);
        const ushort_t* SB = &SLAB[(rsub + di) % 3][0];
#pragma unroll 1
        for (int dj = 0; dj < 3; ++dj) {
            const int tap = di * 3 + dj;
            // ---- issue AS[tap+1] into the other buffer (flies under GEMM)
            if (tap < 8) {
                const ushort_t* wsrc = w2c + (size_t)(tap + 1) * 16384;
#pragma unroll
                for (int it = 0; it < 4; ++it) {
                    const int i = it * 512 + tid;
                    __builtin_amdgcn_global_load_lds((const GLOBAL_AS void*)(wsrc + i * 8),
                                                     (LDS_AS void*)(&AS[(tap + 1) & 1][i * 8]),
                                                     16, 0, 0);
                }
            }

            float kv[4];
#pragma unroll
            for (int ni = 0; ni < 4; ++ni)
                kv[ni] = kg[(size_t)(b * H2 + h) * 1152 + tap * 128 + wn + ni * 16 + l15];

            floatx4 acc[4][4];
#pragma unroll
            for (int mi = 0; mi < 4; ++mi)
#pragma unroll
                for (int ni = 0; ni < 4; ++ni) acc[mi][ni] = (floatx4)0.f;

            const ushort_t* AScur = &AS[tap & 1][0];
#pragma unroll
            for (int kc = 0; kc < 4; ++kc) {
                short8 af[4], bfr[4];
#pragma unroll
                for (int mi = 0; mi < 4; ++mi) {
                    const int row = wm + mi * 16 + l15;
                    af[mi] = *reinterpret_cast<const short8*>(
                        &AScur[row * 128 + (((kc * 4 + quad) ^ (row & 7)) << 3)]);
                }
#pragma unroll
                for (int ni = 0; ni < 4; ++ni) {
                    const int col  = wn + ni * 16 + l15 + dj - 1;
                    const int colc = col & 127;
                    const short8 t = *reinterpret_cast<const short8*>(
                        &SB[colc * 128 + (((kc * 4 + quad) ^ (colc & 7)) << 3)]);
                    const bool ok = hok && (col >= 0) && (col < W2);
                    bfr[ni] = ok ? t : (short8)0;
                }
#pragma unroll
                for (int mi = 0; mi < 4; ++mi)
#pragma unroll
                    for (int ni = 0; ni < 4; ++ni)
                        acc[mi][ni] = __builtin_amdgcn_mfma_f32_16x16x32_bf16(
                            af[mi], bfr[ni], acc[mi][ni], 0, 0, 0);
            }
            // ---- scale by k_tap[w] and accumulate (adds exact 0 for edge taps)
#pragma unroll
            for (int mi = 0; mi < 4; ++mi)
#pragma unroll
                for (int ni = 0; ni < 4; ++ni)
#pragma unroll
                    for (int r = 0; r < 4; ++r)
                        out_acc[mi][ni][r] += kv[ni] * acc[mi][ni][r];

            __syncthreads();   // AS[tap&1] readers done; AS[(tap+1)&1] resident
        }
    }

    // ---- final store: out NCHW fp32
#pragma unroll
    for (int mi = 0; mi < 4; ++mi)
#pragma unroll
        for (int ni = 0; ni < 4; ++ni) {
            const int w = wn + ni * 16 + l15;
#pragma unroll
            for (int r = 0; r < 4; ++r) {
                const int o = wm + mi * 16 + quad * 4 + r;
                out[(((size_t)b * C2 + o) * H2 + h) * W2 + w] = out_acc[mi][ni][r] + b2[o];
            }
        }
}

extern "C" void kernel_launch(void* const* d_in, const int* in_sizes, int n_in,
                              void* d_out, int out_size, void* d_ws, size_t ws_size,
                              hipStream_t stream) {
    const float* x     = (const float*)d_in[0];
    const float* guide = (const float*)d_in[1];
    const float* w1    = (const float*)d_in[2];
    const float* b1    = (const float*)d_in[3];
    const float* w2    = (const float*)d_in[4];
    const float* b2    = (const float*)d_in[5];
    float* out = (float*)d_out;

    ushort_t* w1c = (ushort_t*)((char*)d_ws + W1C_OFF);
    ushort_t* w2c = (ushort_t*)((char*)d_ws + W2C_OFF);
    float*    kg  = (float*)((char*)d_ws + KG_OFF);
    ushort_t* xT  = (ushort_t*)((char*)d_ws + XT_OFF);
    ushort_t* y   = (ushort_t*)((char*)d_ws + Y_OFF);

    prep_kernel<<<PREP_B3, 512, 0, stream>>>(w1, w1c, w2, w2c, x, xT, guide, kg);
    deconv_mfma<<<dim3(64, B_), 512, 0, stream>>>(xT, w1c, b1, y);
    pac_mfma<<<dim3(64, B_), 512, 0, stream>>>(y, kg, w2c, b2, out);
}